// Round 1
// baseline (1885.031 us; speedup 1.0000x reference)
//
#include <hip/hip_runtime.h>

#define S_TOT 30285
#define NTOK 1024
#define DDIM 256
#define QSLOT 100
#define LMAX 30

__device__ __forceinline__ float allred_sum(float v) {
#pragma unroll
  for (int o = 32; o > 0; o >>= 1) v += __shfl_xor(v, o, 64);
  return v;
}
__device__ __forceinline__ float allred_max(float v) {
#pragma unroll
  for (int o = 32; o > 0; o >>= 1) v = fmaxf(v, __shfl_xor(v, o, 64));
  return v;
}

// word_attn[n] = dot(doc[n,:], w) + b
__global__ void k_word_attn(const float* __restrict__ doc, const float* __restrict__ w,
                            const float* __restrict__ b, float* __restrict__ wa) {
  int n = blockIdx.x, t = threadIdx.x;
  float s = 0.f;
  for (int h = t; h < 1024; h += 256) s += doc[n * 1024 + h] * w[h];
  __shared__ float red[256];
  red[t] = s;
  __syncthreads();
  for (int o = 128; o; o >>= 1) {
    if (t < o) red[t] += red[t + o];
    __syncthreads();
  }
  if (t == 0) wa[n] = red[0] + b[0];
}

// Wd[w][d] = sum_j wemb[w][j] * Wp[2048+j][d]
__global__ void k_wd(const float* __restrict__ wemb, const float* __restrict__ wp,
                     float* __restrict__ wd) {
  int w = blockIdx.x, d = threadIdx.x;
  float s = 0.f;
  for (int j = 0; j < 20; j++) s += wemb[w * 20 + j] * wp[(2048 + j) * 256 + d];
  wd[w * 256 + d] = s;
}

// A=doc@Wp[0:1024], B=doc@Wp[1024:2048], C=doc@Wp[2068:3092]
__global__ void k_abc(const float* __restrict__ doc, const float* __restrict__ wp,
                      float* __restrict__ A, float* __restrict__ B, float* __restrict__ C) {
  int rt = blockIdx.x, sec = blockIdx.y, t = threadIdx.x;
  int secoff = (sec == 0) ? 0 : (sec == 1 ? 1024 : 2068);
  float* out = (sec == 0) ? A : (sec == 1 ? B : C);
  __shared__ float dl[8 * 1024];
  for (int e = t; e < 8 * 1024; e += 256)
    dl[e] = doc[(rt * 8 + (e >> 10)) * 1024 + (e & 1023)];
  __syncthreads();
  float acc[8] = {0.f, 0.f, 0.f, 0.f, 0.f, 0.f, 0.f, 0.f};
  const float* w = wp + secoff * 256;
  for (int h = 0; h < 1024; h++) {
    float ww = w[h * 256 + t];
#pragma unroll
    for (int r = 0; r < 8; r++) acc[r] += dl[r * 1024 + h] * ww;
  }
  for (int r = 0; r < 8; r++) out[(rt * 8 + r) * 256 + t] = acc[r];
}

// One block per span-start: x[s] = A[ss] + B[ee] + Wd[width] + bias + sum_p wt[p]*C[ss+p]
__global__ void k_spans(const float* __restrict__ wa, const float* __restrict__ A,
                        const float* __restrict__ B, const float* __restrict__ C,
                        const float* __restrict__ Wd, const float* __restrict__ bias,
                        float* __restrict__ x) {
  int ss = blockIdx.x, t = threadIdx.x;
  int ns = min(30, 1024 - ss);
  int base = (ss < 995) ? ss * 30 : 29850 + 435 - ((1024 - ss) * (1025 - ss)) / 2;
  __shared__ float C_l[30 * 256];
  __shared__ float wa_l[30];
  __shared__ float wt_l[30];
  for (int e = t; e < ns * 256; e += 256)
    C_l[e] = C[(ss + (e >> 8)) * 256 + (e & 255)];
  if (t < ns) wa_l[t] = wa[ss + t];
  __syncthreads();
  float aS = A[ss * 256 + t] + bias[t];
  for (int sp = 0; sp < ns; sp++) {
    if (t < 64) {
      float v = (t <= sp) ? wa_l[t] : -3.4e38f;
      float m = allred_max(v);
      float e = (t <= sp) ? __expf(v - m) : 0.f;
      float s = allred_sum(e);
      if (t <= sp) wt_l[t] = e / s;
    }
    __syncthreads();
    float acc = aS + B[(ss + sp) * 256 + t] + Wd[sp * 256 + t];
    for (int p = 0; p <= sp; p++) acc += wt_l[p] * C_l[p * 256 + t];
    x[(base + sp) * 256 + t] = acc;
    __syncthreads();
  }
}

// in-place rowwise LayerNorm, 4 rows/block (wave per row)
__global__ void k_ln_rows(float* __restrict__ xio, const float* __restrict__ g,
                          const float* __restrict__ be, int nrows) {
  int wave = threadIdx.x >> 6, lane = threadIdx.x & 63;
  int row = blockIdx.x * 4 + wave;
  if (row >= nrows) return;
  float* p = xio + row * 256;
  float v[4];
#pragma unroll
  for (int m = 0; m < 4; m++) v[m] = p[lane + 64 * m];
  float s = v[0] + v[1] + v[2] + v[3];
  s = allred_sum(s);
  float mean = s * (1.f / 256.f);
  float q = 0.f;
#pragma unroll
  for (int m = 0; m < 4; m++) { float d = v[m] - mean; q += d * d; }
  q = allred_sum(q);
  float rstd = rsqrtf(q * (1.f / 256.f) + 1e-5f);
#pragma unroll
  for (int m = 0; m < 4; m++) {
    int c = lane + 64 * m;
    p[c] = (v[m] - mean) * rstd * g[c] + be[c];
  }
}

// k = in@wk+bk ; v = in@wv+bv   (16 rows per block)
__global__ void k_kv(const float* __restrict__ in, const float* __restrict__ wk,
                     const float* __restrict__ bk, const float* __restrict__ wv,
                     const float* __restrict__ bv, float* __restrict__ kb,
                     float* __restrict__ vb, int S_) {
  __shared__ float in_l[16 * 256];
  int r0 = blockIdx.x * 16;
  int t = threadIdx.x;
  for (int e = t; e < 16 * 256; e += 256) {
    int r = r0 + (e >> 8);
    in_l[e] = (r < S_) ? in[r * 256 + (e & 255)] : 0.f;
  }
  __syncthreads();
  float ak[16], av[16];
#pragma unroll
  for (int r = 0; r < 16; r++) { ak[r] = 0.f; av[r] = 0.f; }
  for (int h = 0; h < 256; h++) {
    float a = wk[h * 256 + t], b = wv[h * 256 + t];
#pragma unroll
    for (int r = 0; r < 16; r++) {
      float xx = in_l[r * 256 + h];
      ak[r] += xx * a;
      av[r] += xx * b;
    }
  }
  float bks = bk[t], bvs = bv[t];
  for (int r = 0; r < 16; r++) {
    int rr = r0 + r;
    if (rr < S_) {
      kb[rr * 256 + t] = ak[r] + bks;
      vb[rr * 256 + t] = av[r] + bvs;
    }
  }
}

__global__ void k_vsum(const float* __restrict__ vb, float* __restrict__ vsum, int S_) {
  int t = threadIdx.x, b = blockIdx.x;
  float s = 0.f;
  for (int j = b; j < S_; j += 256) s += vb[j * 256 + t];
  atomicAdd(&vsum[t], s);
}

__global__ void k_copy_slots(const float* __restrict__ sq, float* __restrict__ slots) {
  slots[blockIdx.x * 256 + threadIdx.x] = sq[blockIdx.x * 256 + threadIdx.x];
}

// q = LN(slots; g_sl,be_sl) @ wq + bq   (block per slot)
__global__ void k_qln(const float* __restrict__ slots, const float* __restrict__ g,
                      const float* __restrict__ be, const float* __restrict__ wq,
                      const float* __restrict__ bq, float* __restrict__ q) {
  int i = blockIdx.x, t = threadIdx.x;
  int wave = t >> 6, lane = t & 63;
  __shared__ float red[4];
  __shared__ float ln_l[256];
  float sv = slots[i * 256 + t];
  float s = allred_sum(sv);
  if (lane == 0) red[wave] = s;
  __syncthreads();
  float mean = (red[0] + red[1] + red[2] + red[3]) * (1.f / 256.f);
  float d = sv - mean;
  __syncthreads();
  float s2 = allred_sum(d * d);
  if (lane == 0) red[wave] = s2;
  __syncthreads();
  float var = (red[0] + red[1] + red[2] + red[3]) * (1.f / 256.f);
  float rstd = rsqrtf(var + 1e-5f);
  ln_l[t] = d * rstd * g[t] + be[t];
  __syncthreads();
  float acc = bq[t];
  for (int h = 0; h < 256; h++) acc += ln_l[h] * wq[h * 256 + t];
  q[i * 256 + t] = acc;
}

// dT[j][i] = scale * dot(q[i,:], k[j,:])  -- 32 spans/block, slot chunks of 25
__global__ void k_dots(const float* __restrict__ q, const float* __restrict__ kb,
                       float* __restrict__ dT, int S_) {
  __shared__ float k_l[32 * 257];
  __shared__ float q_l[25 * 257];
  int t = threadIdx.x;
  int j0 = blockIdx.x * 32;
  for (int e = t; e < 32 * 256; e += 256) {
    int jj = e >> 8, c = e & 255;
    int j = j0 + jj;
    k_l[jj * 257 + c] = (j < S_) ? kb[j * 256 + c] : 0.f;
  }
  int jj = t & 31, g = t >> 5;  // 8 groups of slots
  int j = j0 + jj;
  for (int ch = 0; ch < 4; ch++) {
    __syncthreads();
    for (int e = t; e < 25 * 256; e += 256) {
      int r = e >> 8, c = e & 255;
      q_l[r * 257 + c] = q[(ch * 25 + r) * 256 + c];
    }
    __syncthreads();
    float a0 = 0.f, a1 = 0.f, a2 = 0.f, a3 = 0.f;
    for (int h = 0; h < 256; h++) {
      float kk = k_l[jj * 257 + h];
      a0 += kk * q_l[g * 257 + h];
      a1 += kk * q_l[(g + 8) * 257 + h];
      a2 += kk * q_l[(g + 16) * 257 + h];
      if (g == 0) a3 += kk * q_l[24 * 257 + h];
    }
    if (j < S_) {
      dT[j * 100 + ch * 25 + g] = a0 * 0.0625f;
      dT[j * 100 + ch * 25 + g + 8] = a1 * 0.0625f;
      dT[j * 100 + ch * 25 + g + 16] = a2 * 0.0625f;
      if (g == 0) dT[j * 100 + ch * 25 + 24] = a3 * 0.0625f;
    }
  }
}

// per-span softmax over the 100 slots (in place): dT[j][:] -> exp(d-max)/sum
__global__ void k_colsm(float* __restrict__ dT, int S_) {
  int j = blockIdx.x * 256 + threadIdx.x;
  if (j >= S_) return;
  int base = j * 100;
  float m = -3.4e38f;
  for (int i = 0; i < 100; i++) m = fmaxf(m, dT[base + i]);
  float s = 0.f;
  for (int i = 0; i < 100; i++) {
    float e = __expf(dT[base + i] - m);
    dT[base + i] = e;
    s += e;
  }
  float inv = 1.f / s;
  for (int i = 0; i < 100; i++) dT[base + i] *= inv;
}

__global__ void k_rowsum(const float* __restrict__ p, float* __restrict__ rs, int S_) {
  int t = threadIdx.x;
  if (t >= 100) return;
  float s = 0.f;
  for (int j = blockIdx.x; j < S_; j += gridDim.x) s += p[j * 100 + t];
  atomicAdd(&rs[t], s);
}

// uraw[i][d] += sum_j p[j][i] * v[j][d]   grid=(chunks, 4 slot-groups of 25)
__global__ void k_upd(const float* __restrict__ p, const float* __restrict__ vb,
                      float* __restrict__ uraw, int S_) {
  __shared__ float p_l[512 * 25];
  int t = threadIdx.x, ch = blockIdx.x, g = blockIdx.y;
  int r0 = ch * 512;
  int nr = min(512, S_ - r0);
  for (int e = t; e < nr * 25; e += 256) {
    int r = e / 25, c = e % 25;
    p_l[r * 25 + c] = p[(r0 + r) * 100 + g * 25 + c];
  }
  __syncthreads();
  float acc[25];
#pragma unroll
  for (int m = 0; m < 25; m++) acc[m] = 0.f;
  for (int r = 0; r < nr; r++) {
    float vv = vb[(r0 + r) * 256 + t];
#pragma unroll
    for (int m = 0; m < 25; m++) acc[m] += p_l[r * 25 + m] * vv;
  }
#pragma unroll
  for (int m = 0; m < 25; m++) atomicAdd(&uraw[(g * 25 + m) * 256 + t], acc[m]);
}

// GRUCell + LN + MLP residual, block per slot
__global__ void k_gru(const float* __restrict__ uraw, const float* __restrict__ vsum,
                      const float* __restrict__ rs, float* __restrict__ slots,
                      const float* __restrict__ w_ih, const float* __restrict__ w_hh,
                      const float* __restrict__ b_ih, const float* __restrict__ b_hh,
                      const float* __restrict__ w1, const float* __restrict__ b1,
                      const float* __restrict__ w2, const float* __restrict__ b2,
                      const float* __restrict__ g_ff, const float* __restrict__ be_ff) {
  int i = blockIdx.x, t = threadIdx.x;
  int wave = t >> 6, lane = t & 63;
  __shared__ float u_l[256], h_l[256], ff_l[256], hid_l[512];
  __shared__ float red[4];
  const float eps = 1e-8f;
  float u = (uraw[i * 256 + t] + eps * vsum[t]) / (rs[i] + eps * (float)S_TOT);
  float h = slots[i * 256 + t];
  u_l[t] = u;
  h_l[t] = h;
  __syncthreads();
  float gi0 = b_ih[t], gi1 = b_ih[t + 256], gi2 = b_ih[t + 512];
  float gh0 = b_hh[t], gh1 = b_hh[t + 256], gh2 = b_hh[t + 512];
  for (int d = 0; d < 256; d++) {
    float ud = u_l[d], hd = h_l[d];
    gi0 += ud * w_ih[t * 256 + d];
    gi1 += ud * w_ih[(t + 256) * 256 + d];
    gi2 += ud * w_ih[(t + 512) * 256 + d];
    gh0 += hd * w_hh[t * 256 + d];
    gh1 += hd * w_hh[(t + 256) * 256 + d];
    gh2 += hd * w_hh[(t + 512) * 256 + d];
  }
  float rg = 1.f / (1.f + __expf(-(gi0 + gh0)));
  float zg = 1.f / (1.f + __expf(-(gi1 + gh1)));
  float ng = tanhf(gi2 + rg * gh2);
  float ns = (1.f - zg) * ng + zg * h;
  float s = allred_sum(ns);
  if (lane == 0) red[wave] = s;
  __syncthreads();
  float mean = (red[0] + red[1] + red[2] + red[3]) * (1.f / 256.f);
  float dv = ns - mean;
  __syncthreads();
  float s2 = allred_sum(dv * dv);
  if (lane == 0) red[wave] = s2;
  __syncthreads();
  float var = (red[0] + red[1] + red[2] + red[3]) * (1.f / 256.f);
  float rstd = rsqrtf(var + 1e-5f);
  ff_l[t] = dv * rstd * g_ff[t] + be_ff[t];
  __syncthreads();
  float hA = b1[t], hB = b1[t + 256];
  for (int d = 0; d < 256; d++) {
    float f = ff_l[d];
    hA += f * w1[d * 512 + t];
    hB += f * w1[d * 512 + t + 256];
  }
  hid_l[t] = fmaxf(hA, 0.f);
  hid_l[t + 256] = fmaxf(hB, 0.f);
  __syncthreads();
  float o = ns + b2[t];
  for (int c = 0; c < 512; c++) o += hid_l[c] * w2[c * 256 + t];
  slots[i * 256 + t] = o;
}

__global__ void k_coref(const float* __restrict__ p, float* __restrict__ out, int S_) {
  int j = blockIdx.x * 256 + threadIdx.x;
  if (j >= S_) return;
  for (int i = 0; i < 100; i++)
    out[i * S_ + j] = fminf(p[j * 100 + i] + 1e-8f, 1.0f);
}

extern "C" void kernel_launch(void* const* d_in, const int* in_sizes, int n_in,
                              void* d_out, int out_size, void* d_ws, size_t ws_size,
                              hipStream_t stream) {
  const float* doc = (const float*)d_in[0];
  const float* w_wa = (const float*)d_in[3];
  const float* b_wa = (const float*)d_in[4];
  const float* wemb = (const float*)d_in[5];
  const float* wsp = (const float*)d_in[6];
  const float* bsp = (const float*)d_in[7];
  const float* slots_q = (const float*)d_in[8];
  const float* wq = (const float*)d_in[9];
  const float* bq = (const float*)d_in[10];
  const float* wk = (const float*)d_in[11];
  const float* bk = (const float*)d_in[12];
  const float* wv = (const float*)d_in[13];
  const float* bv = (const float*)d_in[14];
  const float* w_ih = (const float*)d_in[15];
  const float* w_hh = (const float*)d_in[16];
  const float* b_ih = (const float*)d_in[17];
  const float* b_hh = (const float*)d_in[18];
  const float* w1 = (const float*)d_in[19];
  const float* b1 = (const float*)d_in[20];
  const float* w2 = (const float*)d_in[21];
  const float* b2 = (const float*)d_in[22];
  const float* g_in = (const float*)d_in[23];
  const float* be_in = (const float*)d_in[24];
  const float* g_sl = (const float*)d_in[25];
  const float* be_sl = (const float*)d_in[26];
  const float* g_ff = (const float*)d_in[27];
  const float* be_ff = (const float*)d_in[28];

  const int S = S_TOT;
  float* out = (float*)d_out;
  float* coref = out;                // 100*S
  float* xin = out + 100 * S;        // S*256 -> becomes `inputs`

  float* ws = (float*)d_ws;
  float* wa = ws;                     // 1024
  float* Wd = wa + 1024;              // 7680
  float* A = Wd + 7680;               // 262144
  float* Bm = A + 262144;             // 262144
  float* Cm = Bm + 262144;            // 262144
  float* kbuf = Cm + 262144;          // S*256
  float* vbuf = kbuf + (size_t)S * 256;   // S*256
  float* dT = vbuf + (size_t)S * 256;     // S*100
  float* vsum = dT + (size_t)S * 100;     // 256
  float* rowsum = vsum + 256;         // 128
  float* uraw = rowsum + 128;         // 25600
  float* slots = uraw + 25600;        // 25600
  float* qbuf = slots + 25600;        // 25600

  k_word_attn<<<1024, 256, 0, stream>>>(doc, w_wa, b_wa, wa);
  k_wd<<<30, 256, 0, stream>>>(wemb, wsp, Wd);
  k_abc<<<dim3(128, 3), 256, 0, stream>>>(doc, wsp, A, Bm, Cm);
  k_spans<<<1024, 256, 0, stream>>>(wa, A, Bm, Cm, Wd, bsp, xin);
  k_ln_rows<<<(S + 3) / 4, 256, 0, stream>>>(xin, g_in, be_in, S);
  k_kv<<<(S + 15) / 16, 256, 0, stream>>>(xin, wk, bk, wv, bv, kbuf, vbuf, S);
  hipMemsetAsync(vsum, 0, 256 * 4, stream);
  k_vsum<<<256, 256, 0, stream>>>(vbuf, vsum, S);
  k_copy_slots<<<100, 256, 0, stream>>>(slots_q, slots);

  for (int it = 0; it < 3; ++it) {
    k_qln<<<100, 256, 0, stream>>>(slots, g_sl, be_sl, wq, bq, qbuf);
    k_dots<<<(S + 31) / 32, 256, 0, stream>>>(qbuf, kbuf, dT, S);
    k_colsm<<<120, 256, 0, stream>>>(dT, S);
    hipMemsetAsync(rowsum, 0, 128 * 4, stream);
    hipMemsetAsync(uraw, 0, 25600 * 4, stream);
    k_rowsum<<<128, 128, 0, stream>>>(dT, rowsum, S);
    k_upd<<<dim3(60, 4), 256, 0, stream>>>(dT, vbuf, uraw, S);
    k_gru<<<100, 256, 0, stream>>>(uraw, vsum, rowsum, slots, w_ih, w_hh, b_ih, b_hh,
                                   w1, b1, w2, b2, g_ff, be_ff);
  }
  k_qln<<<100, 256, 0, stream>>>(slots, g_sl, be_sl, wq, bq, qbuf);
  k_dots<<<(S + 31) / 32, 256, 0, stream>>>(qbuf, kbuf, dT, S);
  k_colsm<<<120, 256, 0, stream>>>(dT, S);
  k_coref<<<119, 256, 0, stream>>>(dT, coref, S);
}

// Round 2
// 543.261 us; speedup vs baseline: 3.4698x; 3.4698x over previous
//
#include <hip/hip_runtime.h>

#define S_TOT 30285
#define SPAD  30720

typedef __attribute__((ext_vector_type(8))) short bf16x8;
typedef __attribute__((ext_vector_type(4))) float f32x4;

__device__ __forceinline__ unsigned short f2bf(float f) {
  unsigned u = __float_as_uint(f);
  u += 0x7FFFu + ((u >> 16) & 1u);
  return (unsigned short)(u >> 16);
}
__device__ __forceinline__ float bf2f(unsigned short h) {
  return __uint_as_float(((unsigned)h) << 16);
}
__device__ __forceinline__ float allred_sum(float v) {
#pragma unroll
  for (int o = 32; o > 0; o >>= 1) v += __shfl_xor(v, o, 64);
  return v;
}
__device__ __forceinline__ float allred_max(float v) {
#pragma unroll
  for (int o = 32; o > 0; o >>= 1) v = fmaxf(v, __shfl_xor(v, o, 64));
  return v;
}

// ---------- prep kernels ----------

__global__ void k_word_attn(const float* __restrict__ doc, const float* __restrict__ w,
                            const float* __restrict__ b, float* __restrict__ wa) {
  int n = blockIdx.x, t = threadIdx.x;
  float s = 0.f;
  for (int h = t; h < 1024; h += 256) s += doc[n * 1024 + h] * w[h];
  __shared__ float red[256];
  red[t] = s;
  __syncthreads();
  for (int o = 128; o; o >>= 1) {
    if (t < o) red[t] += red[t + o];
    __syncthreads();
  }
  if (t == 0) wa[n] = red[0] + b[0];
}

__global__ void k_wd(const float* __restrict__ wemb, const float* __restrict__ wp,
                     float* __restrict__ wd) {
  int w = blockIdx.x, d = threadIdx.x;
  float s = 0.f;
  for (int j = 0; j < 20; j++) s += wemb[w * 20 + j] * wp[(2048 + j) * 256 + d];
  wd[w * 256 + d] = s;
}

__global__ void k_castbf(const float* __restrict__ src, unsigned short* __restrict__ dst, int n) {
  int i = blockIdx.x * 256 + threadIdx.x;
  if (i < n) dst[i] = f2bf(src[i]);
}

// transpose f32 [srcRows][srcCols] -> bf16 [srcCols][srcRows]; dims % 32 == 0
__global__ void k_tcast(const float* __restrict__ src, unsigned short* __restrict__ dst,
                        int srcRows, int srcCols) {
  __shared__ float tile[32][33];
  int r0 = blockIdx.y * 32, c0 = blockIdx.x * 32, t = threadIdx.x;
#pragma unroll
  for (int i = 0; i < 4; i++) {
    int e = i * 256 + t, rr = e >> 5, cc = e & 31;
    tile[rr][cc] = src[(size_t)(r0 + rr) * srcCols + c0 + cc];
  }
  __syncthreads();
#pragma unroll
  for (int i = 0; i < 4; i++) {
    int e = i * 256 + t, cc = e >> 5, rr = e & 31;
    dst[(size_t)(c0 + cc) * srcRows + r0 + rr] = f2bf(tile[rr][cc]);
  }
}

// transpose f32 [srcRows][srcCols] -> f32 [srcCols][srcRows]; dims % 32 == 0
__global__ void k_tposef(const float* __restrict__ src, float* __restrict__ dst,
                         int srcRows, int srcCols) {
  __shared__ float tile[32][33];
  int r0 = blockIdx.y * 32, c0 = blockIdx.x * 32, t = threadIdx.x;
#pragma unroll
  for (int i = 0; i < 4; i++) {
    int e = i * 256 + t, rr = e >> 5, cc = e & 31;
    tile[rr][cc] = src[(size_t)(r0 + rr) * srcCols + c0 + cc];
  }
  __syncthreads();
#pragma unroll
  for (int i = 0; i < 4; i++) {
    int e = i * 256 + t, cc = e >> 5, rr = e & 31;
    dst[(size_t)(c0 + cc) * srcRows + r0 + rr] = tile[rr][cc];
  }
}

// ---------- A/B/C projections: doc[1024,1024] @ wspT_sec^T -> out[1024,256] ----------
__global__ __launch_bounds__(256) void k_abc_mfma(const unsigned short* __restrict__ docb,
                                                  const unsigned short* __restrict__ wspT,
                                                  float* __restrict__ A, float* __restrict__ B,
                                                  float* __restrict__ C) {
  int rt = blockIdx.x, sec = blockIdx.y;
  float* out = sec == 0 ? A : (sec == 1 ? B : C);
  const unsigned short* wt = wspT + (size_t)sec * 256 * 1024;
  __shared__ unsigned short lds[64 * 256];
  int t = threadIdx.x, w = t >> 6, l = t & 63, lr = l & 15, lh = l >> 4;
  f32x4 acc[4][4];
#pragma unroll
  for (int m = 0; m < 4; m++)
#pragma unroll
    for (int n = 0; n < 4; n++) acc[m][n] = (f32x4){0.f, 0.f, 0.f, 0.f};
  for (int kt = 0; kt < 4; kt++) {
    __syncthreads();
#pragma unroll
    for (int it = 0; it < 8; it++) {
      int e = it * 256 + t, row = e >> 5, c16 = e & 31;
      int ba = ((row * 512) + c16 * 16) ^ ((row & 7) << 4);
      *(uint4*)((char*)lds + ba) =
          *(const uint4*)(docb + (size_t)(rt * 64 + row) * 1024 + kt * 256 + c16 * 8);
    }
    __syncthreads();
    for (int kk = 0; kk < 8; kk++) {
      bf16x8 afr[4];
#pragma unroll
      for (int m = 0; m < 4; m++) {
        int row = m * 16 + lr;
        int ba = ((row * 512) + kk * 64 + lh * 16) ^ ((row & 7) << 4);
        afr[m] = *(bf16x8*)((char*)lds + ba);
      }
#pragma unroll
      for (int n = 0; n < 4; n++) {
        bf16x8 b8 = *(const bf16x8*)(wt + (size_t)(w * 64 + n * 16 + lr) * 1024 + kt * 256 +
                                     kk * 32 + lh * 8);
#pragma unroll
        for (int m = 0; m < 4; m++)
          acc[m][n] = __builtin_amdgcn_mfma_f32_16x16x32_bf16(afr[m], b8, acc[m][n], 0, 0, 0);
      }
    }
  }
#pragma unroll
  for (int n = 0; n < 4; n++) {
    int col = w * 64 + n * 16 + lr;
#pragma unroll
    for (int m = 0; m < 4; m++)
#pragma unroll
      for (int r = 0; r < 4; r++)
        out[(size_t)(rt * 64 + m * 16 + lh * 4 + r) * 256 + col] = acc[m][n][r];
  }
}

// ---------- span assembly (f32, unchanged) ----------
__global__ void k_spans(const float* __restrict__ wa, const float* __restrict__ A,
                        const float* __restrict__ B, const float* __restrict__ C,
                        const float* __restrict__ Wd, const float* __restrict__ bias,
                        float* __restrict__ x) {
  int ss = blockIdx.x, t = threadIdx.x;
  int ns = min(30, 1024 - ss);
  int base = (ss < 995) ? ss * 30 : 29850 + 435 - ((1024 - ss) * (1025 - ss)) / 2;
  __shared__ float C_l[30 * 256];
  __shared__ float wa_l[30];
  __shared__ float wt_l[30];
  for (int e = t; e < ns * 256; e += 256)
    C_l[e] = C[(ss + (e >> 8)) * 256 + (e & 255)];
  if (t < ns) wa_l[t] = wa[ss + t];
  __syncthreads();
  float aS = A[ss * 256 + t] + bias[t];
  for (int sp = 0; sp < ns; sp++) {
    if (t < 64) {
      float v = (t <= sp) ? wa_l[t] : -3.4e38f;
      float m = allred_max(v);
      float e = (t <= sp) ? __expf(v - m) : 0.f;
      float s = allred_sum(e);
      if (t <= sp) wt_l[t] = e / s;
    }
    __syncthreads();
    float acc = aS + B[(ss + sp) * 256 + t] + Wd[sp * 256 + t];
    for (int p = 0; p <= sp; p++) acc += wt_l[p] * C_l[p * 256 + t];
    x[(size_t)(base + sp) * 256 + t] = acc;
    __syncthreads();
  }
}

// ---------- LN rows: in-place f32 on xin (rows<S) + bf16 copy padded to SPAD ----------
__global__ void k_ln_rows(float* __restrict__ xio, unsigned short* __restrict__ inb,
                          const float* __restrict__ g, const float* __restrict__ be, int nrows) {
  int wave = threadIdx.x >> 6, lane = threadIdx.x & 63;
  int row = blockIdx.x * 4 + wave;
  if (row >= nrows) {
    if (row < SPAD) {
#pragma unroll
      for (int m = 0; m < 4; m++) inb[(size_t)row * 256 + lane + 64 * m] = 0;
    }
    return;
  }
  float* p = xio + (size_t)row * 256;
  float v[4];
#pragma unroll
  for (int m = 0; m < 4; m++) v[m] = p[lane + 64 * m];
  float s = allred_sum(v[0] + v[1] + v[2] + v[3]);
  float mean = s * (1.f / 256.f);
  float q = 0.f;
#pragma unroll
  for (int m = 0; m < 4; m++) { float d = v[m] - mean; q += d * d; }
  q = allred_sum(q);
  float rstd = rsqrtf(q * (1.f / 256.f) + 1e-5f);
#pragma unroll
  for (int m = 0; m < 4; m++) {
    int c = lane + 64 * m;
    float o = (v[m] - mean) * rstd * g[c] + be[c];
    p[c] = o;
    inb[(size_t)row * 256 + c] = f2bf(o);
  }
}

// ---------- k/v projection, MFMA; writes k row-major bf16 and v transposed bf16 ----------
__global__ __launch_bounds__(256) void k_kv_mfma(const unsigned short* __restrict__ inb,
                                                 const unsigned short* __restrict__ wkT,
                                                 const unsigned short* __restrict__ wvT,
                                                 const float* __restrict__ bk,
                                                 const float* __restrict__ bv,
                                                 unsigned short* __restrict__ kb,
                                                 unsigned short* __restrict__ vT) {
  int j0 = blockIdx.x * 64;
  int t = threadIdx.x, w = t >> 6, l = t & 63, lr = l & 15, lh = l >> 4;
  __shared__ unsigned short lds[64 * 256];
#pragma unroll
  for (int it = 0; it < 8; it++) {
    int e = it * 256 + t, row = e >> 5, c16 = e & 31;
    int ba = ((row * 512) + c16 * 16) ^ ((row & 7) << 4);
    *(uint4*)((char*)lds + ba) = *(const uint4*)(inb + (size_t)(j0 + row) * 256 + c16 * 8);
  }
  __syncthreads();
  f32x4 ak[4][4], av[4][4];
#pragma unroll
  for (int m = 0; m < 4; m++)
#pragma unroll
    for (int n = 0; n < 4; n++) {
      ak[m][n] = (f32x4){0.f, 0.f, 0.f, 0.f};
      av[m][n] = (f32x4){0.f, 0.f, 0.f, 0.f};
    }
  for (int kk = 0; kk < 8; kk++) {
    bf16x8 afr[4];
#pragma unroll
    for (int m = 0; m < 4; m++) {
      int row = m * 16 + lr;
      int ba = ((row * 512) + kk * 64 + lh * 16) ^ ((row & 7) << 4);
      afr[m] = *(bf16x8*)((char*)lds + ba);
    }
#pragma unroll
    for (int n = 0; n < 4; n++) {
      int col = w * 64 + n * 16 + lr;
      bf16x8 bk8 = *(const bf16x8*)(wkT + (size_t)col * 256 + kk * 32 + lh * 8);
      bf16x8 bv8 = *(const bf16x8*)(wvT + (size_t)col * 256 + kk * 32 + lh * 8);
#pragma unroll
      for (int m = 0; m < 4; m++) {
        ak[m][n] = __builtin_amdgcn_mfma_f32_16x16x32_bf16(afr[m], bk8, ak[m][n], 0, 0, 0);
        av[m][n] = __builtin_amdgcn_mfma_f32_16x16x32_bf16(afr[m], bv8, av[m][n], 0, 0, 0);
      }
    }
  }
#pragma unroll
  for (int n = 0; n < 4; n++) {
    int col = w * 64 + n * 16 + lr;
    float bks = bk[col], bvs = bv[col];
#pragma unroll
    for (int m = 0; m < 4; m++)
#pragma unroll
      for (int r = 0; r < 4; r++) {
        int row = j0 + m * 16 + lh * 4 + r;
        kb[(size_t)row * 256 + col] = f2bf(ak[m][n][r] + bks);
        vT[(size_t)col * SPAD + row] = f2bf(av[m][n][r] + bvs);
      }
  }
}

__global__ void k_vsum(const unsigned short* __restrict__ vT, float* __restrict__ vsum, int S_) {
  int d = blockIdx.x, t = threadIdx.x;
  float s = 0.f;
  for (int j = t; j < S_; j += 256) s += bf2f(vT[(size_t)d * SPAD + j]);
  __shared__ float red[256];
  red[t] = s;
  __syncthreads();
  for (int o = 128; o; o >>= 1) {
    if (t < o) red[t] += red[t + o];
    __syncthreads();
  }
  if (t == 0) vsum[d] = red[0];
}

__global__ void k_copy_slots(const float* __restrict__ sq, float* __restrict__ slots) {
  slots[blockIdx.x * 256 + threadIdx.x] = sq[blockIdx.x * 256 + threadIdx.x];
}

// q = LN(slots) @ wq + bq -> bf16 [100 rows of qbf]
__global__ void k_qln(const float* __restrict__ slots, const float* __restrict__ g,
                      const float* __restrict__ be, const float* __restrict__ wq,
                      const float* __restrict__ bq, unsigned short* __restrict__ qbf) {
  int i = blockIdx.x, t = threadIdx.x;
  int wave = t >> 6, lane = t & 63;
  __shared__ float red[4];
  __shared__ float ln_l[256];
  float sv = slots[i * 256 + t];
  float s = allred_sum(sv);
  if (lane == 0) red[wave] = s;
  __syncthreads();
  float mean = (red[0] + red[1] + red[2] + red[3]) * (1.f / 256.f);
  float d = sv - mean;
  __syncthreads();
  float s2 = allred_sum(d * d);
  if (lane == 0) red[wave] = s2;
  __syncthreads();
  float var = (red[0] + red[1] + red[2] + red[3]) * (1.f / 256.f);
  float rstd = rsqrtf(var + 1e-5f);
  ln_l[t] = d * rstd * g[t] + be[t];
  __syncthreads();
  float acc = bq[t];
  for (int h = 0; h < 256; h++) acc += ln_l[h] * wq[h * 256 + t];
  qbf[i * 256 + t] = f2bf(acc);
}

// fused dots(MFMA) + slot-softmax + (pT/rowsum | coref)
__global__ __launch_bounds__(256) void k_dots_f(const unsigned short* __restrict__ kb,
                                                const unsigned short* __restrict__ qb,
                                                unsigned short* __restrict__ pT,
                                                float* __restrict__ rowsum,
                                                float* __restrict__ coref, int final_, int S_) {
  int j0 = blockIdx.x * 64;
  int t = threadIdx.x, w = t >> 6, l = t & 63, lr = l & 15, lh = l >> 4;
  f32x4 acc[7];
#pragma unroll
  for (int n = 0; n < 7; n++) acc[n] = (f32x4){0.f, 0.f, 0.f, 0.f};
  const unsigned short* arow = kb + (size_t)(j0 + w * 16 + lr) * 256;
  for (int kk = 0; kk < 8; kk++) {
    bf16x8 a8 = *(const bf16x8*)(arow + kk * 32 + lh * 8);
#pragma unroll
    for (int n = 0; n < 7; n++) {
      bf16x8 b8 = *(const bf16x8*)(qb + (size_t)(n * 16 + lr) * 256 + kk * 32 + lh * 8);
      acc[n] = __builtin_amdgcn_mfma_f32_16x16x32_bf16(a8, b8, acc[n], 0, 0, 0);
    }
  }
  __shared__ float dt[64][117];
#pragma unroll
  for (int n = 0; n < 7; n++)
#pragma unroll
    for (int r = 0; r < 4; r++) dt[w * 16 + lh * 4 + r][n * 16 + lr] = acc[n][r] * 0.0625f;
  __syncthreads();
  int jj = t >> 2, q4 = t & 3;
  float mx = -3.4e38f;
#pragma unroll
  for (int i = 0; i < 25; i++) mx = fmaxf(mx, dt[jj][q4 * 25 + i]);
  mx = fmaxf(mx, __shfl_xor(mx, 1, 64));
  mx = fmaxf(mx, __shfl_xor(mx, 2, 64));
  float sm = 0.f;
#pragma unroll
  for (int i = 0; i < 25; i++) {
    float e = __expf(dt[jj][q4 * 25 + i] - mx);
    dt[jj][q4 * 25 + i] = e;
    sm += e;
  }
  sm += __shfl_xor(sm, 1, 64);
  sm += __shfl_xor(sm, 2, 64);
  float inv = 1.f / sm;
#pragma unroll
  for (int i = 0; i < 25; i++) dt[jj][q4 * 25 + i] *= inv;
  __syncthreads();
  if (!final_) {
    for (int e = t; e < 112 * 64; e += 256) {
      int i = e >> 6, j2 = e & 63;
      float pv = (i < 100 && (j0 + j2) < S_) ? dt[j2][i] : 0.f;
      pT[(size_t)i * SPAD + j0 + j2] = f2bf(pv);
    }
    int nv = S_ - j0;
    if (nv > 64) nv = 64;
    if (t < 100) {
      float s = 0.f;
      for (int j2 = 0; j2 < nv; j2++) s += dt[j2][t];
      atomicAdd(rowsum + t, s);
    }
  } else {
    for (int e = t; e < 100 * 64; e += 256) {
      int i = e >> 6, j2 = e & 63;
      if ((j0 + j2) < S_) coref[(size_t)i * S_ + j0 + j2] = fminf(dt[j2][i] + 1e-8f, 1.0f);
    }
  }
}

// updates: uraw[i][d] += sum_j pT[i][j] * v[j][d]   (MFMA, split-K atomics)
__global__ __launch_bounds__(256) void k_upd_mfma(const unsigned short* __restrict__ pT,
                                                  const unsigned short* __restrict__ vT,
                                                  float* __restrict__ uraw) {
  int kc = blockIdx.x, ny = blockIdx.y;
  int t = threadIdx.x, w = t >> 6, l = t & 63, lr = l & 15, lh = l >> 4;
  int k0 = kc * 320;
  int c0 = ny * 128 + w * 32;
  f32x4 acc[7][2];
#pragma unroll
  for (int m = 0; m < 7; m++) {
    acc[m][0] = (f32x4){0.f, 0.f, 0.f, 0.f};
    acc[m][1] = (f32x4){0.f, 0.f, 0.f, 0.f};
  }
  for (int ks = 0; ks < 10; ks++) {
    int kof = k0 + ks * 32 + lh * 8;
    bf16x8 b0 = *(const bf16x8*)(vT + (size_t)(c0 + lr) * SPAD + kof);
    bf16x8 b1 = *(const bf16x8*)(vT + (size_t)(c0 + 16 + lr) * SPAD + kof);
#pragma unroll
    for (int m = 0; m < 7; m++) {
      bf16x8 a8 = *(const bf16x8*)(pT + (size_t)(m * 16 + lr) * SPAD + kof);
      acc[m][0] = __builtin_amdgcn_mfma_f32_16x16x32_bf16(a8, b0, acc[m][0], 0, 0, 0);
      acc[m][1] = __builtin_amdgcn_mfma_f32_16x16x32_bf16(a8, b1, acc[m][1], 0, 0, 0);
    }
  }
#pragma unroll
  for (int m = 0; m < 7; m++)
#pragma unroll
    for (int n = 0; n < 2; n++)
#pragma unroll
      for (int r = 0; r < 4; r++) {
        int i = m * 16 + lh * 4 + r;
        if (i < 100) atomicAdd(&uraw[i * 256 + c0 + n * 16 + lr], acc[m][n][r]);
      }
}

// GRUCell + LN + MLP residual
__global__ void k_gru(const float* __restrict__ uraw, const float* __restrict__ vsum,
                      const float* __restrict__ rs, float* __restrict__ slots,
                      const float* __restrict__ w_ihT, const float* __restrict__ w_hhT,
                      const float* __restrict__ b_ih, const float* __restrict__ b_hh,
                      const float* __restrict__ w1, const float* __restrict__ b1,
                      const float* __restrict__ w2, const float* __restrict__ b2,
                      const float* __restrict__ g_ff, const float* __restrict__ be_ff) {
  int i = blockIdx.x, t = threadIdx.x;
  int wave = t >> 6, lane = t & 63;
  __shared__ float u_l[256], h_l[256], ff_l[256], hid_l[512];
  __shared__ float red[4];
  const float eps = 1e-8f;
  float u = (uraw[i * 256 + t] + eps * vsum[t]) / (rs[i] + eps * (float)S_TOT);
  float h = slots[i * 256 + t];
  u_l[t] = u;
  h_l[t] = h;
  __syncthreads();
  float gi0 = b_ih[t], gi1 = b_ih[t + 256], gi2 = b_ih[t + 512];
  float gh0 = b_hh[t], gh1 = b_hh[t + 256], gh2 = b_hh[t + 512];
  for (int d = 0; d < 256; d++) {
    float ud = u_l[d], hd = h_l[d];
    gi0 += ud * w_ihT[d * 768 + t];
    gi1 += ud * w_ihT[d * 768 + 256 + t];
    gi2 += ud * w_ihT[d * 768 + 512 + t];
    gh0 += hd * w_hhT[d * 768 + t];
    gh1 += hd * w_hhT[d * 768 + 256 + t];
    gh2 += hd * w_hhT[d * 768 + 512 + t];
  }
  float rg = 1.f / (1.f + __expf(-(gi0 + gh0)));
  float zg = 1.f / (1.f + __expf(-(gi1 + gh1)));
  float ng = tanhf(gi2 + rg * gh2);
  float ns = (1.f - zg) * ng + zg * h;
  float s = allred_sum(ns);
  if (lane == 0) red[wave] = s;
  __syncthreads();
  float mean = (red[0] + red[1] + red[2] + red[3]) * (1.f / 256.f);
  float dv = ns - mean;
  __syncthreads();
  float s2 = allred_sum(dv * dv);
  if (lane == 0) red[wave] = s2;
  __syncthreads();
  float var = (red[0] + red[1] + red[2] + red[3]) * (1.f / 256.f);
  float rstd = rsqrtf(var + 1e-5f);
  ff_l[t] = dv * rstd * g_ff[t] + be_ff[t];
  __syncthreads();
  float hA = b1[t], hB = b1[t + 256];
  for (int d = 0; d < 256; d++) {
    float f = ff_l[d];
    hA += f * w1[d * 512 + t];
    hB += f * w1[d * 512 + t + 256];
  }
  hid_l[t] = fmaxf(hA, 0.f);
  hid_l[t + 256] = fmaxf(hB, 0.f);
  __syncthreads();
  float o = ns + b2[t];
  for (int c = 0; c < 512; c++) o += hid_l[c] * w2[c * 256 + t];
  slots[i * 256 + t] = o;
}

extern "C" void kernel_launch(void* const* d_in, const int* in_sizes, int n_in,
                              void* d_out, int out_size, void* d_ws, size_t ws_size,
                              hipStream_t stream) {
  const float* doc = (const float*)d_in[0];
  const float* w_wa = (const float*)d_in[3];
  const float* b_wa = (const float*)d_in[4];
  const float* wemb = (const float*)d_in[5];
  const float* wsp = (const float*)d_in[6];
  const float* bsp = (const float*)d_in[7];
  const float* slots_q = (const float*)d_in[8];
  const float* wq = (const float*)d_in[9];
  const float* bq = (const float*)d_in[10];
  const float* wk = (const float*)d_in[11];
  const float* bk = (const float*)d_in[12];
  const float* wv = (const float*)d_in[13];
  const float* bv = (const float*)d_in[14];
  const float* w_ih = (const float*)d_in[15];
  const float* w_hh = (const float*)d_in[16];
  const float* b_ih = (const float*)d_in[17];
  const float* b_hh = (const float*)d_in[18];
  const float* w1 = (const float*)d_in[19];
  const float* b1 = (const float*)d_in[20];
  const float* w2 = (const float*)d_in[21];
  const float* b2 = (const float*)d_in[22];
  const float* g_in = (const float*)d_in[23];
  const float* be_in = (const float*)d_in[24];
  const float* g_sl = (const float*)d_in[25];
  const float* be_sl = (const float*)d_in[26];
  const float* g_ff = (const float*)d_in[27];
  const float* be_ff = (const float*)d_in[28];

  const int S = S_TOT;
  float* out = (float*)d_out;
  float* coref = out;             // 100*S
  float* xin = out + 100 * S;     // S*256 (becomes `inputs`)

  // f32 workspace
  float* ws = (float*)d_ws;
  float* wa = ws;                       // 1024
  float* Wd = wa + 1024;                // 7680
  float* A = Wd + 7680;                 // 262144
  float* Bm = A + 262144;               // 262144
  float* Cm = Bm + 262144;              // 262144
  float* w_ihT = Cm + 262144;           // 196608
  float* w_hhT = w_ihT + 196608;        // 196608
  float* vsum = w_hhT + 196608;         // 256
  float* rowsum = vsum + 256;           // 128
  float* uraw = rowsum + 128;           // 25600
  float* slots = uraw + 25600;          // 25600
  // bf16 workspace
  unsigned short* ub = (unsigned short*)(slots + 25600);
  unsigned short* inb = ub;                         // SPAD*256
  unsigned short* kbuf = inb + (size_t)SPAD * 256;  // SPAD*256
  unsigned short* vT = kbuf + (size_t)SPAD * 256;   // 256*SPAD
  unsigned short* pT = vT + (size_t)SPAD * 256;     // 112*SPAD
  unsigned short* qbf = pT + (size_t)112 * SPAD;    // 112*256
  unsigned short* docb = qbf + 112 * 256;           // 1024*1024
  unsigned short* wspT = docb + 1024 * 1024;        // 768*1024
  unsigned short* wkT = wspT + 768 * 1024;          // 256*256
  unsigned short* wvT = wkT + 256 * 256;            // 256*256

  k_word_attn<<<1024, 256, 0, stream>>>(doc, w_wa, b_wa, wa);
  k_wd<<<30, 256, 0, stream>>>(wemb, wsp, Wd);
  k_castbf<<<4096, 256, 0, stream>>>(doc, docb, 1024 * 1024);
  k_tcast<<<dim3(8, 32), 256, 0, stream>>>(wsp, wspT, 1024, 256);
  k_tcast<<<dim3(8, 32), 256, 0, stream>>>(wsp + 1024 * 256, wspT + 256 * 1024, 1024, 256);
  k_tcast<<<dim3(8, 32), 256, 0, stream>>>(wsp + 2068 * 256, wspT + 512 * 1024, 1024, 256);
  k_tcast<<<dim3(8, 8), 256, 0, stream>>>(wk, wkT, 256, 256);
  k_tcast<<<dim3(8, 8), 256, 0, stream>>>(wv, wvT, 256, 256);
  k_tposef<<<dim3(8, 24), 256, 0, stream>>>(w_ih, w_ihT, 768, 256);
  k_tposef<<<dim3(8, 24), 256, 0, stream>>>(w_hh, w_hhT, 768, 256);
  k_abc_mfma<<<dim3(16, 3), 256, 0, stream>>>(docb, wspT, A, Bm, Cm);
  k_spans<<<1024, 256, 0, stream>>>(wa, A, Bm, Cm, Wd, bsp, xin);
  k_ln_rows<<<SPAD / 4, 256, 0, stream>>>(xin, inb, g_in, be_in, S);
  k_kv_mfma<<<SPAD / 64, 256, 0, stream>>>(inb, wkT, wvT, bk, bv, kbuf, vT);
  k_vsum<<<256, 256, 0, stream>>>(vT, vsum, S);
  k_copy_slots<<<100, 256, 0, stream>>>(slots_q, slots);

  for (int it = 0; it < 3; ++it) {
    k_qln<<<100, 256, 0, stream>>>(slots, g_sl, be_sl, wq, bq, qbf);
    hipMemsetAsync(rowsum, 0, 128 * 4, stream);
    hipMemsetAsync(uraw, 0, 25600 * 4, stream);
    k_dots_f<<<SPAD / 64, 256, 0, stream>>>(kbuf, qbf, pT, rowsum, coref, 0, S);
    k_upd_mfma<<<dim3(96, 2), 256, 0, stream>>>(pT, vT, uraw);
    k_gru<<<100, 256, 0, stream>>>(uraw, vsum, rowsum, slots, w_ihT, w_hhT, b_ih, b_hh,
                                   w1, b1, w2, b2, g_ff, be_ff);
  }
  k_qln<<<100, 256, 0, stream>>>(slots, g_sl, be_sl, wq, bq, qbf);
  k_dots_f<<<SPAD / 64, 256, 0, stream>>>(kbuf, qbf, pT, rowsum, coref, 1, S);
}

// Round 3
// 488.415 us; speedup vs baseline: 3.8595x; 1.1123x over previous
//
#include <hip/hip_runtime.h>

#define S_TOT 30285
#define SPAD  30720
#define EPS_S 3.0285e-4f  // 1e-8 * S_TOT

typedef __attribute__((ext_vector_type(8))) short bf16x8;
typedef __attribute__((ext_vector_type(4))) float f32x4;

__device__ __forceinline__ unsigned short f2bf(float f) {
  unsigned u = __float_as_uint(f);
  u += 0x7FFFu + ((u >> 16) & 1u);
  return (unsigned short)(u >> 16);
}
__device__ __forceinline__ float allred_sum(float v) {
#pragma unroll
  for (int o = 32; o > 0; o >>= 1) v += __shfl_xor(v, o, 64);
  return v;
}

// ---------- prep ----------

__global__ void k_word_attn(const float* __restrict__ doc, const float* __restrict__ w,
                            const float* __restrict__ b, float* __restrict__ wa) {
  int n = blockIdx.x, t = threadIdx.x;
  float s = 0.f;
  for (int h = t; h < 1024; h += 256) s += doc[n * 1024 + h] * w[h];
  __shared__ float red[256];
  red[t] = s;
  __syncthreads();
  for (int o = 128; o; o >>= 1) {
    if (t < o) red[t] += red[t + o];
    __syncthreads();
  }
  if (t == 0) wa[n] = red[0] + b[0];
}

__global__ void k_wd(const float* __restrict__ wemb, const float* __restrict__ wp,
                     float* __restrict__ wd) {
  int w = blockIdx.x, d = threadIdx.x;
  float s = 0.f;
  for (int j = 0; j < 20; j++) s += wemb[w * 20 + j] * wp[(2048 + j) * 256 + d];
  wd[w * 256 + d] = s;
}

// one kernel: cast doc, w_ih, w_hh to bf16 (row-major kept)
__global__ void k_cast3(const float* __restrict__ doc, const float* __restrict__ wih,
                        const float* __restrict__ whh, unsigned short* __restrict__ docb,
                        unsigned short* __restrict__ wihb, unsigned short* __restrict__ whhb) {
  int b = blockIdx.x, t = threadIdx.x;
  if (b < 4096) {
    int i = b * 256 + t;
    docb[i] = f2bf(doc[i]);
  } else if (b < 4864) {
    int i = (b - 4096) * 256 + t;
    wihb[i] = f2bf(wih[i]);
  } else {
    int i = (b - 4864) * 256 + t;
    whhb[i] = f2bf(whh[i]);
  }
}

// one kernel: all f32[R][C] -> bf16[C][R] transposed casts
__global__ void k_tcast_all(const float* __restrict__ wsp, const float* __restrict__ wk,
                            const float* __restrict__ wv, const float* __restrict__ wq,
                            const float* __restrict__ w1, const float* __restrict__ w2,
                            unsigned short* __restrict__ wspT, unsigned short* __restrict__ wkT,
                            unsigned short* __restrict__ wvT, unsigned short* __restrict__ wqT,
                            unsigned short* __restrict__ w1T, unsigned short* __restrict__ w2T) {
  int b = blockIdx.x, t = threadIdx.x;
  const float* src;
  unsigned short* dst;
  int R, C, tid;
  if (b < 768) {
    int sec = b >> 8;
    tid = b & 255;
    src = wsp + (sec == 0 ? 0 : (sec == 1 ? 1024 * 256 : 2068 * 256));
    dst = wspT + (size_t)sec * 256 * 1024;
    R = 1024; C = 256;
  } else if (b < 832) { src = wk; dst = wkT; R = 256; C = 256; tid = b - 768; }
  else if (b < 896) { src = wv; dst = wvT; R = 256; C = 256; tid = b - 832; }
  else if (b < 960) { src = wq; dst = wqT; R = 256; C = 256; tid = b - 896; }
  else if (b < 1088) { src = w1; dst = w1T; R = 256; C = 512; tid = b - 960; }
  else { src = w2; dst = w2T; R = 512; C = 256; tid = b - 1088; }
  int cw = C >> 5;
  int c0 = (tid % cw) * 32, r0 = (tid / cw) * 32;
  __shared__ float tile[32][33];
#pragma unroll
  for (int i = 0; i < 4; i++) {
    int e = i * 256 + t, rr = e >> 5, cc = e & 31;
    tile[rr][cc] = src[(size_t)(r0 + rr) * C + c0 + cc];
  }
  __syncthreads();
#pragma unroll
  for (int i = 0; i < 4; i++) {
    int e = i * 256 + t, cc = e >> 5, rr = e & 31;
    dst[(size_t)(c0 + cc) * R + r0 + rr] = f2bf(tile[rr][cc]);
  }
}

// A/B/C projections: doc @ wsp sections (MFMA)
__global__ __launch_bounds__(256) void k_abc_mfma(const unsigned short* __restrict__ docb,
                                                  const unsigned short* __restrict__ wspT,
                                                  float* __restrict__ A, float* __restrict__ B,
                                                  float* __restrict__ C) {
  int rt = blockIdx.x, sec = blockIdx.y;
  float* out = sec == 0 ? A : (sec == 1 ? B : C);
  const unsigned short* wt = wspT + (size_t)sec * 256 * 1024;
  __shared__ unsigned short lds[64 * 256];
  int t = threadIdx.x, w = t >> 6, l = t & 63, lr = l & 15, lh = l >> 4;
  f32x4 acc[4][4];
#pragma unroll
  for (int m = 0; m < 4; m++)
#pragma unroll
    for (int n = 0; n < 4; n++) acc[m][n] = (f32x4){0.f, 0.f, 0.f, 0.f};
  for (int kt = 0; kt < 4; kt++) {
    __syncthreads();
#pragma unroll
    for (int it = 0; it < 8; it++) {
      int e = it * 256 + t, row = e >> 5, c16 = e & 31;
      int ba = ((row * 512) + c16 * 16) ^ ((row & 7) << 4);
      *(uint4*)((char*)lds + ba) =
          *(const uint4*)(docb + (size_t)(rt * 64 + row) * 1024 + kt * 256 + c16 * 8);
    }
    __syncthreads();
    for (int kk = 0; kk < 8; kk++) {
      bf16x8 afr[4];
#pragma unroll
      for (int m = 0; m < 4; m++) {
        int row = m * 16 + lr;
        int ba = ((row * 512) + kk * 64 + lh * 16) ^ ((row & 7) << 4);
        afr[m] = *(bf16x8*)((char*)lds + ba);
      }
#pragma unroll
      for (int n = 0; n < 4; n++) {
        bf16x8 b8 = *(const bf16x8*)(wt + (size_t)(w * 64 + n * 16 + lr) * 1024 + kt * 256 +
                                     kk * 32 + lh * 8);
#pragma unroll
        for (int m = 0; m < 4; m++)
          acc[m][n] = __builtin_amdgcn_mfma_f32_16x16x32_bf16(afr[m], b8, acc[m][n], 0, 0, 0);
      }
    }
  }
#pragma unroll
  for (int n = 0; n < 4; n++) {
    int col = w * 64 + n * 16 + lr;
#pragma unroll
    for (int m = 0; m < 4; m++)
#pragma unroll
      for (int r = 0; r < 4; r++)
        out[(size_t)(rt * 64 + m * 16 + lh * 4 + r) * 256 + col] = acc[m][n][r];
  }
}

// spans: online-softmax prefix weights + fused input-LN; writes xin f32 + inb bf16
__global__ void k_spans_ln(const float* __restrict__ wa, const float* __restrict__ A,
                           const float* __restrict__ B, const float* __restrict__ C,
                           const float* __restrict__ Wd, const float* __restrict__ bias,
                           const float* __restrict__ g_in, const float* __restrict__ be_in,
                           float* __restrict__ xin, unsigned short* __restrict__ inb) {
  int ss = blockIdx.x, t = threadIdx.x;
  int wave = t >> 6, lane = t & 63;
  int nsp = min(30, 1024 - ss);
  int base = (ss < 995) ? ss * 30 : 29850 + 435 - ((1024 - ss) * (1025 - ss)) / 2;
  __shared__ float C_l[30 * 256];
  __shared__ float wa_l[30];
  __shared__ float red[8];
  for (int e = t; e < nsp * 256; e += 256)
    C_l[e] = C[(ss + (e >> 8)) * 256 + (e & 255)];
  if (t < nsp) wa_l[t] = wa[ss + t];
  __syncthreads();
  float aS = A[ss * 256 + t] + bias[t];
  float gg = g_in[t], bb = be_in[t];
  float m = -3.4e38f, Z = 0.f, W = 0.f;
  for (int sp = 0; sp < nsp; sp++) {
    float as_ = wa_l[sp];
    float mn = fmaxf(m, as_);
    float corr = __expf(m - mn);
    float e = __expf(as_ - mn);
    Z = Z * corr + e;
    W = W * corr + e * C_l[sp * 256 + t];
    m = mn;
    float val = aS + B[(ss + sp) * 256 + t] + Wd[sp * 256 + t] + W / Z;
    float s = allred_sum(val);
    if (lane == 0) red[wave] = s;
    __syncthreads();
    float mean = (red[0] + red[1] + red[2] + red[3]) * (1.f / 256.f);
    float dv = val - mean;
    float s2 = allred_sum(dv * dv);
    if (lane == 0) red[4 + wave] = s2;
    __syncthreads();
    float var = (red[4] + red[5] + red[6] + red[7]) * (1.f / 256.f);
    float o = dv * rsqrtf(var + 1e-5f) * gg + bb;
    size_t r = (size_t)(base + sp) * 256 + t;
    xin[r] = o;
    inb[r] = f2bf(o);
    __syncthreads();
  }
}

// k/v projection MFMA; k row-major bf16, v transposed bf16; vsum fused
__global__ __launch_bounds__(256) void k_kv_mfma(const unsigned short* __restrict__ inb,
                                                 const unsigned short* __restrict__ wkT,
                                                 const unsigned short* __restrict__ wvT,
                                                 const float* __restrict__ bk,
                                                 const float* __restrict__ bv,
                                                 unsigned short* __restrict__ kb,
                                                 unsigned short* __restrict__ vT,
                                                 float* __restrict__ vsum) {
  int j0 = blockIdx.x * 64;
  int t = threadIdx.x, w = t >> 6, l = t & 63, lr = l & 15, lh = l >> 4;
  __shared__ unsigned short lds[64 * 256];
#pragma unroll
  for (int it = 0; it < 8; it++) {
    int e = it * 256 + t, row = e >> 5, c16 = e & 31;
    int ba = ((row * 512) + c16 * 16) ^ ((row & 7) << 4);
    *(uint4*)((char*)lds + ba) = *(const uint4*)(inb + (size_t)(j0 + row) * 256 + c16 * 8);
  }
  __syncthreads();
  f32x4 ak[4][4], av[4][4];
#pragma unroll
  for (int m = 0; m < 4; m++)
#pragma unroll
    for (int n = 0; n < 4; n++) {
      ak[m][n] = (f32x4){0.f, 0.f, 0.f, 0.f};
      av[m][n] = (f32x4){0.f, 0.f, 0.f, 0.f};
    }
  for (int kk = 0; kk < 8; kk++) {
    bf16x8 afr[4];
#pragma unroll
    for (int m = 0; m < 4; m++) {
      int row = m * 16 + lr;
      int ba = ((row * 512) + kk * 64 + lh * 16) ^ ((row & 7) << 4);
      afr[m] = *(bf16x8*)((char*)lds + ba);
    }
#pragma unroll
    for (int n = 0; n < 4; n++) {
      int col = w * 64 + n * 16 + lr;
      bf16x8 bk8 = *(const bf16x8*)(wkT + (size_t)col * 256 + kk * 32 + lh * 8);
      bf16x8 bv8 = *(const bf16x8*)(wvT + (size_t)col * 256 + kk * 32 + lh * 8);
#pragma unroll
      for (int m = 0; m < 4; m++) {
        ak[m][n] = __builtin_amdgcn_mfma_f32_16x16x32_bf16(afr[m], bk8, ak[m][n], 0, 0, 0);
        av[m][n] = __builtin_amdgcn_mfma_f32_16x16x32_bf16(afr[m], bv8, av[m][n], 0, 0, 0);
      }
    }
  }
#pragma unroll
  for (int n = 0; n < 4; n++) {
    int col = w * 64 + n * 16 + lr;
    float bks = bk[col], bvs = bv[col];
    float cs = 0.f;
#pragma unroll
    for (int m = 0; m < 4; m++)
#pragma unroll
      for (int r = 0; r < 4; r++) {
        int row = j0 + m * 16 + lh * 4 + r;
        float kvv = ak[m][n][r] + bks;
        float vvv = av[m][n][r] + bvs;
        kb[(size_t)row * 256 + col] = f2bf(kvv);
        vT[(size_t)col * SPAD + row] = f2bf(vvv);
        if (row < S_TOT) cs += vvv;
      }
    cs += __shfl_xor(cs, 16, 64);
    cs += __shfl_xor(cs, 32, 64);
    if (lh == 0) atomicAdd(&vsum[col], cs);
  }
}

// LN(slots) with g_sl -> lnsl bf16; slots -> h bf16; optional copy src->slots
__global__ void k_lnq(const float* __restrict__ src, float* __restrict__ slots_w,
                      unsigned short* __restrict__ lnslb, unsigned short* __restrict__ hbf,
                      const float* __restrict__ g, const float* __restrict__ be, int do_copy) {
  int i = blockIdx.x, t = threadIdx.x;
  if (i >= 100) {
    lnslb[i * 256 + t] = 0;
    hbf[i * 256 + t] = 0;
    return;
  }
  int wave = t >> 6, lane = t & 63;
  __shared__ float red[8];
  float v = src[i * 256 + t];
  if (do_copy) slots_w[i * 256 + t] = v;
  hbf[i * 256 + t] = f2bf(v);
  float s = allred_sum(v);
  if (lane == 0) red[wave] = s;
  __syncthreads();
  float mean = (red[0] + red[1] + red[2] + red[3]) * (1.f / 256.f);
  float dv = v - mean;
  float s2 = allred_sum(dv * dv);
  if (lane == 0) red[4 + wave] = s2;
  __syncthreads();
  float var = (red[4] + red[5] + red[6] + red[7]) * (1.f / 256.f);
  float rstd = rsqrtf(var + 1e-5f);
  lnslb[i * 256 + t] = f2bf(dv * rstd * g[t] + be[t]);
}

// q = lnsl @ wq + bq (MFMA); block 0 zeroes rowsum
__global__ __launch_bounds__(256) void k_qmm(const unsigned short* __restrict__ lnslb,
                                             const unsigned short* __restrict__ wqT,
                                             const float* __restrict__ bq,
                                             unsigned short* __restrict__ qbf,
                                             float* __restrict__ rowsum) {
  int t = threadIdx.x;
  if (blockIdx.x == 0 && t < 128) rowsum[t] = 0.f;
  int w = t >> 6, l = t & 63, lr = l & 15, lh = l >> 4;
  int col = blockIdx.x * 64 + w * 16 + lr;
  f32x4 acc[7];
#pragma unroll
  for (int m = 0; m < 7; m++) acc[m] = (f32x4){0.f, 0.f, 0.f, 0.f};
  for (int kk = 0; kk < 8; kk++) {
    int d0 = kk * 32 + lh * 8;
    bf16x8 b8 = *(const bf16x8*)(wqT + (size_t)col * 256 + d0);
#pragma unroll
    for (int m = 0; m < 7; m++) {
      bf16x8 a8 = *(const bf16x8*)(lnslb + (size_t)(m * 16 + lr) * 256 + d0);
      acc[m] = __builtin_amdgcn_mfma_f32_16x16x32_bf16(a8, b8, acc[m], 0, 0, 0);
    }
  }
  float bb = bq[col];
#pragma unroll
  for (int m = 0; m < 7; m++)
#pragma unroll
    for (int r = 0; r < 4; r++)
      qbf[(size_t)(m * 16 + lh * 4 + r) * 256 + col] = f2bf(acc[m][r] + bb);
}

// fused dots(MFMA) + slot-softmax + (pT/rowsum | coref); block 0 zeroes uraw
__global__ __launch_bounds__(256) void k_dots_f(const unsigned short* __restrict__ kb,
                                                const unsigned short* __restrict__ qb,
                                                unsigned short* __restrict__ pT,
                                                float* __restrict__ rowsum,
                                                float* __restrict__ uraw,
                                                float* __restrict__ coref, int final_, int S_) {
  int j0 = blockIdx.x * 64;
  int t = threadIdx.x, w = t >> 6, l = t & 63, lr = l & 15, lh = l >> 4;
  if (!final_ && blockIdx.x == 0) {
    for (int e = t; e < 112 * 256; e += 256) uraw[e] = 0.f;
  }
  f32x4 acc[7];
#pragma unroll
  for (int n = 0; n < 7; n++) acc[n] = (f32x4){0.f, 0.f, 0.f, 0.f};
  const unsigned short* arow = kb + (size_t)(j0 + w * 16 + lr) * 256;
  for (int kk = 0; kk < 8; kk++) {
    bf16x8 a8 = *(const bf16x8*)(arow + kk * 32 + lh * 8);
#pragma unroll
    for (int n = 0; n < 7; n++) {
      bf16x8 b8 = *(const bf16x8*)(qb + (size_t)(n * 16 + lr) * 256 + kk * 32 + lh * 8);
      acc[n] = __builtin_amdgcn_mfma_f32_16x16x32_bf16(a8, b8, acc[n], 0, 0, 0);
    }
  }
  __shared__ float dt[64][117];
#pragma unroll
  for (int n = 0; n < 7; n++)
#pragma unroll
    for (int r = 0; r < 4; r++) dt[w * 16 + lh * 4 + r][n * 16 + lr] = acc[n][r] * 0.0625f;
  __syncthreads();
  int jj = t >> 2, q4 = t & 3;
  float mx = -3.4e38f;
#pragma unroll
  for (int i = 0; i < 25; i++) mx = fmaxf(mx, dt[jj][q4 * 25 + i]);
  mx = fmaxf(mx, __shfl_xor(mx, 1, 64));
  mx = fmaxf(mx, __shfl_xor(mx, 2, 64));
  float sm = 0.f;
#pragma unroll
  for (int i = 0; i < 25; i++) {
    float e = __expf(dt[jj][q4 * 25 + i] - mx);
    dt[jj][q4 * 25 + i] = e;
    sm += e;
  }
  sm += __shfl_xor(sm, 1, 64);
  sm += __shfl_xor(sm, 2, 64);
  float inv = 1.f / sm;
#pragma unroll
  for (int i = 0; i < 25; i++) dt[jj][q4 * 25 + i] *= inv;
  __syncthreads();
  if (!final_) {
    for (int e = t; e < 112 * 64; e += 256) {
      int i = e >> 6, j2 = e & 63;
      float pv = (i < 100 && (j0 + j2) < S_) ? dt[j2][i] : 0.f;
      pT[(size_t)i * SPAD + j0 + j2] = f2bf(pv);
    }
    int nv = S_ - j0;
    if (nv > 64) nv = 64;
    if (t < 100) {
      float s = 0.f;
      for (int j2 = 0; j2 < nv; j2++) s += dt[j2][t];
      atomicAdd(rowsum + t, s);
    }
  } else {
    for (int e = t; e < 100 * 64; e += 256) {
      int i = e >> 6, j2 = e & 63;
      if ((j0 + j2) < S_) coref[(size_t)i * S_ + j0 + j2] = fminf(dt[j2][i] + 1e-8f, 1.0f);
    }
  }
}

// updates: uraw += pT @ v (MFMA split-K atomics)
__global__ __launch_bounds__(256) void k_upd_mfma(const unsigned short* __restrict__ pT,
                                                  const unsigned short* __restrict__ vT,
                                                  float* __restrict__ uraw) {
  int kc = blockIdx.x, ny = blockIdx.y;
  int t = threadIdx.x, w = t >> 6, l = t & 63, lr = l & 15, lh = l >> 4;
  int k0 = kc * 320;
  int c0 = ny * 128 + w * 32;
  f32x4 acc[7][2];
#pragma unroll
  for (int m = 0; m < 7; m++) {
    acc[m][0] = (f32x4){0.f, 0.f, 0.f, 0.f};
    acc[m][1] = (f32x4){0.f, 0.f, 0.f, 0.f};
  }
  for (int ks = 0; ks < 10; ks++) {
    int kof = k0 + ks * 32 + lh * 8;
    bf16x8 b0 = *(const bf16x8*)(vT + (size_t)(c0 + lr) * SPAD + kof);
    bf16x8 b1 = *(const bf16x8*)(vT + (size_t)(c0 + 16 + lr) * SPAD + kof);
#pragma unroll
    for (int m = 0; m < 7; m++) {
      bf16x8 a8 = *(const bf16x8*)(pT + (size_t)(m * 16 + lr) * SPAD + kof);
      acc[m][0] = __builtin_amdgcn_mfma_f32_16x16x32_bf16(a8, b0, acc[m][0], 0, 0, 0);
      acc[m][1] = __builtin_amdgcn_mfma_f32_16x16x32_bf16(a8, b1, acc[m][1], 0, 0, 0);
    }
  }
#pragma unroll
  for (int m = 0; m < 7; m++)
#pragma unroll
    for (int n = 0; n < 2; n++)
#pragma unroll
      for (int r = 0; r < 4; r++) {
        int i = m * 16 + lh * 4 + r;
        if (i < 100) atomicAdd(&uraw[i * 256 + c0 + n * 16 + lr], acc[m][n][r]);
      }
}

// gates: gi = u@w_ih^T + b_ih, gh = h@w_hh^T + b_hh (MFMA); u normalized on the fly
__global__ __launch_bounds__(256) void k_gates(
    const float* __restrict__ uraw, const float* __restrict__ vsum,
    const float* __restrict__ rs, const unsigned short* __restrict__ hbf,
    const unsigned short* __restrict__ wihb, const unsigned short* __restrict__ whhb,
    const float* __restrict__ b_ih, const float* __restrict__ b_hh,
    float* __restrict__ gi, float* __restrict__ gh) {
  int x = blockIdx.x, y = blockIdx.y;
  const unsigned short* Wt = y ? whhb : wihb;
  const float* bias = y ? b_hh : b_ih;
  float* out = y ? gh : gi;
  int t = threadIdx.x, w = t >> 6, l = t & 63, lr = l & 15, lh = l >> 4;
  int c0 = x * 128 + w * 32;
  f32x4 acc[7][2];
#pragma unroll
  for (int m = 0; m < 7; m++) {
    acc[m][0] = (f32x4){0.f, 0.f, 0.f, 0.f};
    acc[m][1] = (f32x4){0.f, 0.f, 0.f, 0.f};
  }
  for (int kk = 0; kk < 8; kk++) {
    int d0 = kk * 32 + lh * 8;
    bf16x8 a8[7];
    if (y) {
#pragma unroll
      for (int m = 0; m < 7; m++)
        a8[m] = *(const bf16x8*)(hbf + (size_t)(m * 16 + lr) * 256 + d0);
    } else {
      float4 vs0 = *(const float4*)(vsum + d0);
      float4 vs1 = *(const float4*)(vsum + d0 + 4);
#pragma unroll
      for (int m = 0; m < 7; m++) {
        int row = m * 16 + lr;
        float inv = 1.f / (rs[row] + EPS_S);
        float4 u0 = *(const float4*)(uraw + row * 256 + d0);
        float4 u1 = *(const float4*)(uraw + row * 256 + d0 + 4);
        bf16x8 a;
        a[0] = (short)f2bf((u0.x + 1e-8f * vs0.x) * inv);
        a[1] = (short)f2bf((u0.y + 1e-8f * vs0.y) * inv);
        a[2] = (short)f2bf((u0.z + 1e-8f * vs0.z) * inv);
        a[3] = (short)f2bf((u0.w + 1e-8f * vs0.w) * inv);
        a[4] = (short)f2bf((u1.x + 1e-8f * vs1.x) * inv);
        a[5] = (short)f2bf((u1.y + 1e-8f * vs1.y) * inv);
        a[6] = (short)f2bf((u1.z + 1e-8f * vs1.z) * inv);
        a[7] = (short)f2bf((u1.w + 1e-8f * vs1.w) * inv);
        a8[m] = a;
      }
    }
#pragma unroll
    for (int n = 0; n < 2; n++) {
      bf16x8 b8 = *(const bf16x8*)(Wt + (size_t)(c0 + n * 16 + lr) * 256 + d0);
#pragma unroll
      for (int m = 0; m < 7; m++)
        acc[m][n] = __builtin_amdgcn_mfma_f32_16x16x32_bf16(a8[m], b8, acc[m][n], 0, 0, 0);
    }
  }
#pragma unroll
  for (int n = 0; n < 2; n++) {
    int col = c0 + n * 16 + lr;
    float bb = bias[col];
#pragma unroll
    for (int m = 0; m < 7; m++)
#pragma unroll
      for (int r = 0; r < 4; r++)
        out[(size_t)(m * 16 + lh * 4 + r) * 768 + col] = acc[m][n][r] + bb;
  }
}

// GRU elementwise + LN_ff -> ff bf16; stores ns f32
__global__ void k_gru2a(const float* __restrict__ gi, const float* __restrict__ gh,
                        const float* __restrict__ slots, float* __restrict__ nsb,
                        unsigned short* __restrict__ ffb, const float* __restrict__ g_ff,
                        const float* __restrict__ be_ff) {
  int i = blockIdx.x, t = threadIdx.x;
  if (i >= 100) {
    ffb[i * 256 + t] = 0;
    return;
  }
  int wave = t >> 6, lane = t & 63;
  __shared__ float red[8];
  float gi0 = gi[i * 768 + t], gi1 = gi[i * 768 + 256 + t], gi2 = gi[i * 768 + 512 + t];
  float gh0 = gh[i * 768 + t], gh1 = gh[i * 768 + 256 + t], gh2 = gh[i * 768 + 512 + t];
  float h = slots[i * 256 + t];
  float rg = 1.f / (1.f + __expf(-(gi0 + gh0)));
  float zg = 1.f / (1.f + __expf(-(gi1 + gh1)));
  float ng = tanhf(gi2 + rg * gh2);
  float ns_ = (1.f - zg) * ng + zg * h;
  nsb[i * 256 + t] = ns_;
  float s = allred_sum(ns_);
  if (lane == 0) red[wave] = s;
  __syncthreads();
  float mean = (red[0] + red[1] + red[2] + red[3]) * (1.f / 256.f);
  float dv = ns_ - mean;
  float s2 = allred_sum(dv * dv);
  if (lane == 0) red[4 + wave] = s2;
  __syncthreads();
  float var = (red[4] + red[5] + red[6] + red[7]) * (1.f / 256.f);
  float o = dv * rsqrtf(var + 1e-5f) * g_ff[t] + be_ff[t];
  ffb[i * 256 + t] = f2bf(o);
}

// hid = relu(ff @ w1 + b1) -> bf16
__global__ __launch_bounds__(256) void k_mlp1(const unsigned short* __restrict__ ffb,
                                              const unsigned short* __restrict__ w1T,
                                              const float* __restrict__ b1,
                                              unsigned short* __restrict__ hidb) {
  int t = threadIdx.x, w = t >> 6, l = t & 63, lr = l & 15, lh = l >> 4;
  int col = blockIdx.x * 64 + w * 16 + lr;
  f32x4 acc[7];
#pragma unroll
  for (int m = 0; m < 7; m++) acc[m] = (f32x4){0.f, 0.f, 0.f, 0.f};
  for (int kk = 0; kk < 8; kk++) {
    int d0 = kk * 32 + lh * 8;
    bf16x8 b8 = *(const bf16x8*)(w1T + (size_t)col * 256 + d0);
#pragma unroll
    for (int m = 0; m < 7; m++) {
      bf16x8 a8 = *(const bf16x8*)(ffb + (size_t)(m * 16 + lr) * 256 + d0);
      acc[m] = __builtin_amdgcn_mfma_f32_16x16x32_bf16(a8, b8, acc[m], 0, 0, 0);
    }
  }
  float bb = b1[col];
#pragma unroll
  for (int m = 0; m < 7; m++)
#pragma unroll
    for (int r = 0; r < 4; r++)
      hidb[(size_t)(m * 16 + lh * 4 + r) * 512 + col] = f2bf(fmaxf(acc[m][r] + bb, 0.f));
}

// slots = ns + hid @ w2 + b2
__global__ __launch_bounds__(256) void k_mlp2(const unsigned short* __restrict__ hidb,
                                              const unsigned short* __restrict__ w2T,
                                              const float* __restrict__ b2,
                                              const float* __restrict__ nsb,
                                              float* __restrict__ slots) {
  int t = threadIdx.x, w = t >> 6, l = t & 63, lr = l & 15, lh = l >> 4;
  int col = blockIdx.x * 64 + w * 16 + lr;
  f32x4 acc[7];
#pragma unroll
  for (int m = 0; m < 7; m++) acc[m] = (f32x4){0.f, 0.f, 0.f, 0.f};
  for (int kk = 0; kk < 16; kk++) {
    int d0 = kk * 32 + lh * 8;
    bf16x8 b8 = *(const bf16x8*)(w2T + (size_t)col * 512 + d0);
#pragma unroll
    for (int m = 0; m < 7; m++) {
      bf16x8 a8 = *(const bf16x8*)(hidb + (size_t)(m * 16 + lr) * 512 + d0);
      acc[m] = __builtin_amdgcn_mfma_f32_16x16x32_bf16(a8, b8, acc[m], 0, 0, 0);
    }
  }
  float bb = b2[col];
#pragma unroll
  for (int m = 0; m < 7; m++)
#pragma unroll
    for (int r = 0; r < 4; r++) {
      int i = m * 16 + lh * 4 + r;
      if (i < 100) slots[i * 256 + col] = acc[m][r] + bb + nsb[i * 256 + col];
    }
}

extern "C" void kernel_launch(void* const* d_in, const int* in_sizes, int n_in,
                              void* d_out, int out_size, void* d_ws, size_t ws_size,
                              hipStream_t stream) {
  const float* doc = (const float*)d_in[0];
  const float* w_wa = (const float*)d_in[3];
  const float* b_wa = (const float*)d_in[4];
  const float* wemb = (const float*)d_in[5];
  const float* wsp = (const float*)d_in[6];
  const float* bsp = (const float*)d_in[7];
  const float* slots_q = (const float*)d_in[8];
  const float* wq = (const float*)d_in[9];
  const float* bq = (const float*)d_in[10];
  const float* wk = (const float*)d_in[11];
  const float* bk = (const float*)d_in[12];
  const float* wv = (const float*)d_in[13];
  const float* bv = (const float*)d_in[14];
  const float* w_ih = (const float*)d_in[15];
  const float* w_hh = (const float*)d_in[16];
  const float* b_ih = (const float*)d_in[17];
  const float* b_hh = (const float*)d_in[18];
  const float* w1 = (const float*)d_in[19];
  const float* b1 = (const float*)d_in[20];
  const float* w2 = (const float*)d_in[21];
  const float* b2 = (const float*)d_in[22];
  const float* g_in = (const float*)d_in[23];
  const float* be_in = (const float*)d_in[24];
  const float* g_sl = (const float*)d_in[25];
  const float* be_sl = (const float*)d_in[26];
  const float* g_ff = (const float*)d_in[27];
  const float* be_ff = (const float*)d_in[28];

  const int S = S_TOT;
  float* out = (float*)d_out;
  float* coref = out;          // 100*S
  float* xin = out + 100 * S;  // S*256 (LN'd `inputs`)

  // f32 workspace
  float* ws = (float*)d_ws;
  float* wa = ws;                 // 1024
  float* Wd = wa + 1024;          // 7680
  float* A = Wd + 7680;           // 262144
  float* Bm = A + 262144;         // 262144
  float* Cm = Bm + 262144;        // 262144
  float* vsum = Cm + 262144;      // 256
  float* rowsum = vsum + 256;     // 128
  float* uraw = rowsum + 128;     // 28672 (112 rows)
  float* slots = uraw + 28672;    // 25600
  float* nsb = slots + 25600;     // 28672
  float* gi = nsb + 28672;        // 86016
  float* gh = gi + 86016;         // 86016
  // bf16 workspace
  unsigned short* ub = (unsigned short*)(gh + 86016);
  unsigned short* inb = ub;                           // SPAD*256
  unsigned short* kbuf = inb + (size_t)SPAD * 256;    // SPAD*256
  unsigned short* vT = kbuf + (size_t)SPAD * 256;     // 256*SPAD
  unsigned short* pT = vT + (size_t)SPAD * 256;       // 112*SPAD
  unsigned short* qbf = pT + (size_t)112 * SPAD;      // 112*256
  unsigned short* docb = qbf + 112 * 256;             // 1024*1024
  unsigned short* wspT = docb + 1024 * 1024;          // 768*1024
  unsigned short* wkT = wspT + 768 * 1024;            // 256*256
  unsigned short* wvT = wkT + 256 * 256;              // 256*256
  unsigned short* wqT = wvT + 256 * 256;              // 256*256
  unsigned short* wihb = wqT + 256 * 256;             // 768*256
  unsigned short* whhb = wihb + 768 * 256;            // 768*256
  unsigned short* w1T = whhb + 768 * 256;             // 512*256
  unsigned short* w2T = w1T + 512 * 256;              // 256*512
  unsigned short* hbf = w2T + 256 * 512;              // 112*256
  unsigned short* lnslb = hbf + 112 * 256;            // 112*256
  unsigned short* ffb = lnslb + 112 * 256;            // 112*256
  unsigned short* hidb = ffb + 112 * 256;             // 112*512

  k_word_attn<<<1024, 256, 0, stream>>>(doc, w_wa, b_wa, wa);
  k_wd<<<30, 256, 0, stream>>>(wemb, wsp, Wd);
  k_cast3<<<5632, 256, 0, stream>>>(doc, w_ih, w_hh, docb, wihb, whhb);
  k_tcast_all<<<1216, 256, 0, stream>>>(wsp, wk, wv, wq, w1, w2, wspT, wkT, wvT, wqT, w1T, w2T);
  hipMemsetAsync(vsum, 0, 384 * 4, stream);  // vsum + rowsum
  hipMemsetAsync(inb + (size_t)S * 256, 0, (size_t)(SPAD - S) * 256 * 2, stream);
  k_abc_mfma<<<dim3(16, 3), 256, 0, stream>>>(docb, wspT, A, Bm, Cm);
  k_spans_ln<<<1024, 256, 0, stream>>>(wa, A, Bm, Cm, Wd, bsp, g_in, be_in, xin, inb);
  k_kv_mfma<<<SPAD / 64, 256, 0, stream>>>(inb, wkT, wvT, bk, bv, kbuf, vT, vsum);
  k_lnq<<<112, 256, 0, stream>>>(slots_q, slots, lnslb, hbf, g_sl, be_sl, 1);

  for (int it = 0; it < 3; ++it) {
    k_qmm<<<4, 256, 0, stream>>>(lnslb, wqT, bq, qbf, rowsum);
    k_dots_f<<<SPAD / 64, 256, 0, stream>>>(kbuf, qbf, pT, rowsum, uraw, coref, 0, S);
    k_upd_mfma<<<dim3(96, 2), 256, 0, stream>>>(pT, vT, uraw);
    k_gates<<<dim3(6, 2), 256, 0, stream>>>(uraw, vsum, rowsum, hbf, wihb, whhb, b_ih, b_hh,
                                            gi, gh);
    k_gru2a<<<112, 256, 0, stream>>>(gi, gh, slots, nsb, ffb, g_ff, be_ff);
    k_mlp1<<<8, 256, 0, stream>>>(ffb, w1T, b1, hidb);
    k_mlp2<<<4, 256, 0, stream>>>(hidb, w2T, b2, nsb, slots);
    k_lnq<<<112, 256, 0, stream>>>(slots, slots, lnslb, hbf, g_sl, be_sl, 0);
  }
  k_qmm<<<4, 256, 0, stream>>>(lnslb, wqT, bq, qbf, rowsum);
  k_dots_f<<<SPAD / 64, 256, 0, stream>>>(kbuf, qbf, pT, rowsum, uraw, coref, 1, S);
}